// Round 10
// baseline (12168.100 us; speedup 1.0000x reference)
//
#include <hip/hip_runtime.h>
#include <stdint.h>

#define NP 25088   // B * oH * oW = 8*56*56
#define DD 576     // 64 * 3 * 3
#define KC 256     // centroids

// ---------------- unfold: x[8,64,56,56] -> P^T[576][25088], d = c*9+i*3+j ----
__global__ __launch_bounds__(256) void unfold_kernel(const float* __restrict__ x,
                                                     float* __restrict__ PT) {
  const int d = blockIdx.y;                       // 0..575
  const int n = blockIdx.x * 256 + threadIdx.x;   // 0..25087
  const int c = d / 9, r = d % 9;
  const int di = r / 3 - 1, dj = r % 3 - 1;
  const int b = n / 3136, hw = n % 3136;
  const int h = hw / 56 + di, w = hw % 56 + dj;
  float v = 0.0f;
  if (h >= 0 && h < 56 && w >= 0 && w < 56)
    v = x[(((size_t)b * 64 + c) * 56 + h) * 56 + w];
  PT[(size_t)d * NP + n] = v;
}

// ---------------- centroid transpose: C[256][576] -> C^T[576][256] -----------
__global__ __launch_bounds__(256) void transpose_kernel(const float* __restrict__ C,
                                                        float* __restrict__ CT) {
  const int d = blockIdx.x;      // 576
  const int k = threadIdx.x;     // 256
  CT[d * KC + k] = C[k * DD + d];
}

// ---------------- nearest: barrier-free wave-private pipeline ----------------
// Wave owns 32m x 32k; thread tile 4m x 4k (R4's proven core). Per-wave
// PRIVATE double-buffered LDS tiles (Dc=8) -> DS ops are same-wave in-order,
// so NO __syncthreads anywhere: no lockstep chunk drains (R4's stall), no
// reg-rotation spills (R9's failure; staging is 2 float4s only).
// 16 KB LDS / 256-thr block, launch_bounds(256,8) -> 8 blocks/CU = 32 waves/CU.
// Grid 1568 = 196 m-groups(128) x 8 k-slabs; kc = blockIdx & 7 pins one k-slab
// per XCD (B-slab 73 KB L2-resident; A streams via L3).
// Cross-slab argmin: atomicMin on packed u64 (distbits<<32 | k): dist >= 0 so
// float bits are order-monotone; ties -> lowest k = reference first-min,
// dispatch-order independent.
#define ACC4(p, a, s) \
  do { p.x += fabsf(a.x - (s)); p.y += fabsf(a.y - (s)); \
       p.z += fabsf(a.z - (s)); p.w += fabsf(a.w - (s)); } while (0)
#define ADD4(t, p) \
  do { t.x += p.x; t.y += p.y; t.z += p.z; t.w += p.w; } while (0)
#define COMP(v, i) ((i) == 0 ? (v).x : (i) == 1 ? (v).y : (i) == 2 ? (v).z : (v).w)

__global__ __launch_bounds__(256, 8) void nearest_kernel(const float* __restrict__ AT,
                                                         const float* __restrict__ CT,
                                                         unsigned long long* __restrict__ keys) {
  __shared__ __align__(16) float As[4][2][8][32];  // [wave][buf][d][m]  8 KB
  __shared__ __align__(16) float Bs[4][2][8][32];  // [wave][buf][d][k]  8 KB

  const int tid = threadIdx.x;
  const int wv = tid >> 6, lane = tid & 63;
  const int tm = lane >> 3, tk = lane & 7;       // 8x8 thread grid in wave
  const int kc = blockIdx.x & 7;                 // k-slab == XCD
  const int mg = blockIdx.x >> 3;                // 0..195
  const int m0 = mg * 128 + wv * 32;
  const int k0 = kc * 32;

  // staging lane map: row dr (of 8), 4-col group cl; LDS offset = lane*16 B
  const int dr = lane >> 3, cl = (lane & 7) * 4;
  const float* ap = AT + (size_t)dr * NP + m0 + cl;
  const float* bp = CT + (size_t)dr * KC + k0 + cl;
  float* aw = &As[wv][0][dr][cl];                // buf stride = 256 floats
  float* bw = &Bs[wv][0][dr][cl];

  // all state named float4 (R3/R4 lesson: arrays => scratch)
  float4 ra, rb;
  float4 p0, p1, p2, p3, t0, t1, t2, t3;

#define LOADT() do { ra = *(const float4*)ap; rb = *(const float4*)bp;   \
                     ap += (size_t)8 * NP; bp += 8 * KC; } while (0)
#define WRITET(bf) do { *(float4*)(aw + (bf) * 256) = ra;                \
                        *(float4*)(bw + (bf) * 256) = rb; } while (0)

  LOADT();
  WRITET(0);
  t0 = t1 = t2 = t3 = make_float4(0.f, 0.f, 0.f, 0.f);

#pragma unroll 2
  for (int ch = 0; ch < 72; ++ch) {              // 72 * 8 = 576 d's
    if ((ch & 7) == 0) p0 = p1 = p2 = p3 = make_float4(0.f, 0.f, 0.f, 0.f);
    if (ch < 71) LOADT();                        // issue next-chunk globals
    const float* Ab = &As[wv][ch & 1][0][0];
    const float* Bb = &Bs[wv][ch & 1][0][0];
#pragma unroll
    for (int d = 0; d < 8; ++d) {
      const float4 a = *(const float4*)(Ab + d * 32 + tm * 4);  // 8-way bcast
      const float4 b = *(const float4*)(Bb + d * 32 + tk * 4);  // 8-way bcast
      ACC4(p0, a, b.x);
      ACC4(p1, a, b.y);
      ACC4(p2, a, b.z);
      ACC4(p3, a, b.w);
    }
    if (ch < 71) WRITET((ch + 1) & 1);           // same-wave DS order: safe
    if ((ch & 7) == 7) {                         // 64-d segment flush
      ADD4(t0, p0); ADD4(t1, p1); ADD4(t2, p2); ADD4(t3, p3);
    }
  }

  // per-thread argmin over 4 k's (ascending, strict < => first-min), butterfly
  // over the 8 tk lanes of this m-row, then one packed atomicMin per (m,slab).
#pragma unroll
  for (int i = 0; i < 4; ++i) {
    float bd = COMP(t0, i);
    int bk = k0 + tk * 4;
    float dj;
    dj = COMP(t1, i); if (dj < bd) { bd = dj; bk = k0 + tk * 4 + 1; }
    dj = COMP(t2, i); if (dj < bd) { bd = dj; bk = k0 + tk * 4 + 2; }
    dj = COMP(t3, i); if (dj < bd) { bd = dj; bk = k0 + tk * 4 + 3; }
#pragma unroll
    for (int off = 1; off < 8; off <<= 1) {
      const float od = __shfl_xor(bd, off, 64);
      const int ok = __shfl_xor(bk, off, 64);
      if (od < bd || (od == bd && ok < bk)) { bd = od; bk = ok; }
    }
    if (tk == 0) {
      const unsigned long long key =
          ((unsigned long long)__float_as_uint(bd) << 32) | (unsigned)bk;
      atomicMin(&keys[m0 + tm * 4 + i], key);
    }
  }
#undef LOADT
#undef WRITET
}

// ---------------- residual in place: P^T[d][n] -= C1^T[d][k(keys[n])] --------
__global__ __launch_bounds__(256) void resid_kernel(float* __restrict__ PT,
                                                    const float* __restrict__ C1T,
                                                    const unsigned long long* __restrict__ keys) {
  const int d = blockIdx.y;
  const int n = blockIdx.x * 256 + threadIdx.x;
  const int k = (int)(keys[n] & 0xffffffffULL);
  PT[(size_t)d * NP + n] -= C1T[d * KC + k];
}

// ---------------- BN stats: per-channel sum & sumsq of LUT outputs -----------
__global__ __launch_bounds__(256) void stats_kernel(const unsigned long long* __restrict__ keys1,
                                                    const unsigned long long* __restrict__ keys2,
                                                    const float* __restrict__ dotc,
                                                    const float* __restrict__ dotrc,
                                                    float* __restrict__ gsum,
                                                    float* __restrict__ gsq) {
  __shared__ float ssum[4][128], ssq[4][128];
  const int tid = threadIdx.x, lane = tid & 63, wv = tid >> 6;
  const int wid = blockIdx.x * 4 + wv;           // 0..511
  float s0 = 0.f, s1 = 0.f, q0 = 0.f, q1 = 0.f;
  for (int n = wid; n < NP; n += 512) {          // 25088 = 512*49
    const int k1 = (int)(keys1[n] & 0xffffffffULL);
    const int k2 = (int)(keys2[n] & 0xffffffffULL);
    const float2 u = ((const float2*)(dotc + (size_t)k1 * 128))[lane];
    const float2 v = ((const float2*)(dotrc + (size_t)k2 * 128))[lane];
    const float x0 = u.x + v.x, x1 = u.y + v.y;
    s0 += x0; s1 += x1; q0 += x0 * x0; q1 += x1 * x1;
  }
  ssum[wv][lane * 2] = s0; ssum[wv][lane * 2 + 1] = s1;
  ssq[wv][lane * 2] = q0;  ssq[wv][lane * 2 + 1] = q1;
  __syncthreads();
  if (tid < 128) {
    const float s = ssum[0][tid] + ssum[1][tid] + ssum[2][tid] + ssum[3][tid];
    const float q = ssq[0][tid] + ssq[1][tid] + ssq[2][tid] + ssq[3][tid];
    atomicAdd(&gsum[tid], s);
    atomicAdd(&gsq[tid], q);
  }
}

__global__ void finalize_kernel(const float* __restrict__ gsum,
                                const float* __restrict__ gsq,
                                const float* __restrict__ gamma,
                                const float* __restrict__ beta,
                                float* __restrict__ scalev,
                                float* __restrict__ shiftv) {
  const int c = threadIdx.x;                     // 128
  const float mean = gsum[c] * (1.0f / NP);
  const float var = gsq[c] * (1.0f / NP) - mean * mean;
  const float inv = rsqrtf(var + 1e-5f);
  const float sc = gamma[c] * inv;
  scalev[c] = sc;
  shiftv[c] = beta[c] - mean * sc;
}

// ---------------- output: LUT gather + affine BN + [B,C,H,W] store -----------
__global__ __launch_bounds__(256) void output_kernel(const unsigned long long* __restrict__ keys1,
                                                     const unsigned long long* __restrict__ keys2,
                                                     const float* __restrict__ dotc,
                                                     const float* __restrict__ dotrc,
                                                     const float* __restrict__ scalev,
                                                     const float* __restrict__ shiftv,
                                                     float* __restrict__ out) {
  __shared__ float vals[64][128];                // [n-local][c]  32 KB
  const int tid = threadIdx.x, lane = tid & 63, wv = tid >> 6;
  const int blk = blockIdx.x;                    // 392 = 8 * 49
  const int b = blk / 49, hw0 = (blk % 49) * 64;
  const int n0 = b * 3136 + hw0;
  const float sc0 = scalev[lane * 2], sc1 = scalev[lane * 2 + 1];
  const float sh0 = shiftv[lane * 2], sh1 = shiftv[lane * 2 + 1];
  for (int t = 0; t < 16; ++t) {
    const int nn = wv * 16 + t;
    const int n = n0 + nn;
    const int k1 = (int)(keys1[n] & 0xffffffffULL);
    const int k2 = (int)(keys2[n] & 0xffffffffULL);
    const float2 u = ((const float2*)(dotc + (size_t)k1 * 128))[lane];
    const float2 v = ((const float2*)(dotrc + (size_t)k2 * 128))[lane];
    *(float2*)&vals[nn][lane * 2] =
        make_float2(sc0 * (u.x + v.x) + sh0, sc1 * (u.y + v.y) + sh1);
  }
  __syncthreads();
  const int c = tid >> 1, half = tid & 1;
  float* op = out + ((size_t)b * 128 + c) * 3136 + hw0 + half * 32;
#pragma unroll
  for (int i = 0; i < 32; i += 4) {
    float4 w4;
    w4.x = vals[half * 32 + i + 0][c];
    w4.y = vals[half * 32 + i + 1][c];
    w4.z = vals[half * 32 + i + 2][c];
    w4.w = vals[half * 32 + i + 3][c];
    *(float4*)(op + i) = w4;
  }
}

extern "C" void kernel_launch(void* const* d_in, const int* in_sizes, int n_in,
                              void* d_out, int out_size, void* d_ws, size_t ws_size,
                              hipStream_t stream) {
  const float* x     = (const float*)d_in[0];
  const float* cent  = (const float*)d_in[1];
  const float* rcent = (const float*)d_in[2];
  const float* dotc  = (const float*)d_in[3];
  const float* dotrc = (const float*)d_in[4];
  const float* gamma = (const float*)d_in[5];
  const float* beta  = (const float*)d_in[6];
  float* out = (float*)d_out;

  // workspace layout (~59.6 MB)
  float* PT  = (float*)d_ws;                            // [576][25088]
  float* C1T = PT + (size_t)DD * NP;                    // [576][256]
  float* C2T = C1T + (size_t)DD * KC;                   // [576][256]
  unsigned long long* keys1 = (unsigned long long*)(C2T + (size_t)DD * KC);
  unsigned long long* keys2 = keys1 + NP;
  float* gsum   = (float*)(keys2 + NP);                 // [128]
  float* gsq    = gsum + 128;                           // [128]
  float* scalev = gsq + 128;                            // [128]
  float* shiftv = scalev + 128;                         // [128]

  unfold_kernel<<<dim3(98, 576), 256, 0, stream>>>(x, PT);
  transpose_kernel<<<576, 256, 0, stream>>>(cent, C1T);
  transpose_kernel<<<576, 256, 0, stream>>>(rcent, C2T);
  hipMemsetAsync(keys1, 0xFF, 2 * NP * sizeof(unsigned long long), stream);
  nearest_kernel<<<1568, 256, 0, stream>>>(PT, C1T, keys1);
  resid_kernel<<<dim3(98, 576), 256, 0, stream>>>(PT, C1T, keys1);
  nearest_kernel<<<1568, 256, 0, stream>>>(PT, C2T, keys2);
  hipMemsetAsync(gsum, 0, 256 * sizeof(float), stream);
  stats_kernel<<<128, 256, 0, stream>>>(keys1, keys2, dotc, dotrc, gsum, gsq);
  finalize_kernel<<<1, 128, 0, stream>>>(gsum, gsq, gamma, beta, scalev, shiftv);
  output_kernel<<<392, 256, 0, stream>>>(keys1, keys2, dotc, dotrc, scalev, shiftv, out);
}

// Round 11
// 2117.020 us; speedup vs baseline: 5.7477x; 5.7477x over previous
//
#include <hip/hip_runtime.h>

#define NP 25088   // B * oH * oW = 8*56*56
#define DD 576     // 64 * 3 * 3
#define KC 256     // centroids

// ---------------- unfold: x[8,64,56,56] -> P^T[576][25088], d = c*9+i*3+j ----
__global__ __launch_bounds__(256) void unfold_kernel(const float* __restrict__ x,
                                                     float* __restrict__ PT) {
  const int d = blockIdx.y;                       // 0..575
  const int n = blockIdx.x * 256 + threadIdx.x;   // 0..25087
  const int c = d / 9, r = d % 9;
  const int di = r / 3 - 1, dj = r % 3 - 1;
  const int b = n / 3136, hw = n % 3136;
  const int h = hw / 56 + di, w = hw % 56 + dj;
  float v = 0.0f;
  if (h >= 0 && h < 56 && w >= 0 && w < 56)
    v = x[(((size_t)b * 64 + c) * 56 + h) * 56 + w];
  PT[(size_t)d * NP + n] = v;
}

// ---------------- centroid transpose: C[256][576] -> C^T[576][256] -----------
__global__ __launch_bounds__(256) void transpose_kernel(const float* __restrict__ C,
                                                        float* __restrict__ CT) {
  const int d = blockIdx.x;      // 576
  const int k = threadIdx.x;     // 256
  CT[d * KC + k] = C[k * DD + d];
}

// ---------------- nearest: per-block best over a 64-k slab -------------------
// R4 config restored verbatim (best of 10 rounds: 287 us/dispatch, VGPR 44,
// zero scratch): 64m x 64k block, 4m x 4k thread tile, Dc=32 double-buffered,
// 32 KB LDS -> 5 blocks/CU = 20 waves/CU, grid 1568 = 392 m-groups x 4
// k-slabs, XCD-chunk swizzled, launch_bounds(256,5).
// R11 delta (instruction-stream only): 9 segments x 2 compile-time chunks
// (parity/flush branch-free) + fully unrolled 32-d compute (scheduler hoists
// all 64 ds_read_b128 per chunk). Structure untouched.
// FAILED departures (do not revisit): 4m x 8k @12w (R5), Dc=16 @24w (R6),
// global_load_lds DMA (R7), scalar-feed (R8), reg-dbuf rotation (R9),
// launch_bounds cap 64 -> spill catastrophe (R10).
#define ACC4(p, a, s) \
  do { p.x += fabsf(a.x - (s)); p.y += fabsf(a.y - (s)); \
       p.z += fabsf(a.z - (s)); p.w += fabsf(a.w - (s)); } while (0)
#define ADD4(t, p) \
  do { t.x += p.x; t.y += p.y; t.z += p.z; t.w += p.w; } while (0)
#define COMP(v, i) ((i) == 0 ? (v).x : (i) == 1 ? (v).y : (i) == 2 ? (v).z : (v).w)

__global__ __launch_bounds__(256, 5) void nearest_kernel(const float* __restrict__ AT,
                                                         const float* __restrict__ CT,
                                                         float* __restrict__ distc,
                                                         int* __restrict__ idxc) {
  __shared__ float As[2][32][64];    // [buf][d][m]   16 KB
  __shared__ float Bs[2][32][64];    // [buf][d][k]   16 KB

  const int tid = threadIdx.x;
  const int tm = tid >> 4;           // 0..15 -> m = m0 + tm*4 + i
  const int tk = tid & 15;           // 0..15 -> k = k0 + tk*4 + j
  // XCD-chunk swizzle: XCD x gets m-groups [49x, 49x+49), 4 k-slabs adjacent.
  const int L = blockIdx.x;          // 0..1567 (= 8 * 196)
  const int xcd = L & 7, r = L >> 3;     // r 0..195
  const int mb = xcd * 49 + (r >> 2);    // 0..391
  const int kc = r & 3;                  // 0..3
  const int m0 = mb * 64, k0 = kc * 64;

  // staging + accumulators: named float4 only (no local arrays anywhere)
  float4 ra0, ra1, rb0, rb1;
  float4 p0, p1, p2, p3, t0, t1, t2, t3;

  const int frow = tid >> 4, fcol = (tid & 15) * 4;
  const float* ap = AT + (size_t)frow * NP + m0 + fcol;   // rows frow, frow+16
  const float* bp = CT + (size_t)frow * KC + k0 + fcol;

#define LOADT() do {                                       \
    ra0 = *(const float4*)(ap);                            \
    ra1 = *(const float4*)(ap + (size_t)16 * NP);          \
    rb0 = *(const float4*)(bp);                            \
    rb1 = *(const float4*)(bp + 16 * KC);                  \
    ap += (size_t)32 * NP; bp += 32 * KC;                  \
  } while (0)

#define WRITET(bf) do {                                    \
    *(float4*)&As[bf][frow][fcol] = ra0;                   \
    *(float4*)&As[bf][16 + frow][fcol] = ra1;              \
    *(float4*)&Bs[bf][frow][fcol] = rb0;                   \
    *(float4*)&Bs[bf][16 + frow][fcol] = rb1;              \
  } while (0)

// one chunk: barrier, prefetch-issue, 32-d fully-unrolled compute, write-next.
// bf = compile-time buffer index (0/1); LAST = compile-time tail flag.
#define CHUNK(bf, LAST) do {                               \
    __syncthreads();                                       \
    if (!(LAST)) LOADT();                                  \
    {                                                      \
      const float (*__restrict__ Asb)[64] = As[bf];        \
      const float (*__restrict__ Bsb)[64] = Bs[bf];        \
      _Pragma("unroll")                                    \
      for (int d = 0; d < 32; ++d) {                       \
        const float4 a = *(const float4*)&Asb[d][tm * 4];  \
        const float4 b = *(const float4*)&Bsb[d][tk * 4];  \
        ACC4(p0, a, b.x);                                  \
        ACC4(p1, a, b.y);                                  \
        ACC4(p2, a, b.z);                                  \
        ACC4(p3, a, b.w);                                  \
      }                                                    \
    }                                                      \
    if (!(LAST)) WRITET(1 - (bf));                         \
  } while (0)

  LOADT();
  WRITET(0);
  t0 = t1 = t2 = t3 = make_float4(0.f, 0.f, 0.f, 0.f);

#pragma unroll 1
  for (int seg = 0; seg < 9; ++seg) {          // 9 segs x 2 chunks x 32 d = 576
    p0 = p1 = p2 = p3 = make_float4(0.f, 0.f, 0.f, 0.f);
    CHUNK(0, false);
    if (seg < 8) {
      CHUNK(1, false);
    } else {
      CHUNK(1, true);                          // tail: no prefetch/write
    }
    ADD4(t0, p0); ADD4(t1, p1); ADD4(t2, p2); ADD4(t3, p3);  // 64-d flush
  }

  // per-thread argmin over its 4 k's (ascending, strict < => first-min),
  // then butterfly reduce across the 16 tk lanes sharing this m-row.
#pragma unroll
  for (int i = 0; i < 4; ++i) {
    const float d0 = COMP(t0, i), d1 = COMP(t1, i), d2 = COMP(t2, i), d3 = COMP(t3, i);
    float bd = d0;
    int bk = k0 + tk * 4;
    if (d1 < bd) { bd = d1; bk = k0 + tk * 4 + 1; }
    if (d2 < bd) { bd = d2; bk = k0 + tk * 4 + 2; }
    if (d3 < bd) { bd = d3; bk = k0 + tk * 4 + 3; }
#pragma unroll
    for (int off = 1; off < 16; off <<= 1) {
      const float od = __shfl_xor(bd, off, 64);
      const int ok = __shfl_xor(bk, off, 64);
      if (od < bd || (od == bd && ok < bk)) { bd = od; bk = ok; }
    }
    if (tk == 0) {
      const int m = m0 + tm * 4 + i;
      distc[(size_t)kc * NP + m] = bd;
      idxc[(size_t)kc * NP + m] = bk;
    }
  }
#undef LOADT
#undef WRITET
#undef CHUNK
}

// ---------------- combine the four k-slab candidates (tie -> lower k) --------
__global__ __launch_bounds__(256) void combine_kernel(const float* __restrict__ distc,
                                                      const int* __restrict__ idxc,
                                                      int* __restrict__ idx_out) {
  const int n = blockIdx.x * 256 + threadIdx.x;
  if (n >= NP) return;
  float bd = distc[n];
  int bi = idxc[n];
#pragma unroll
  for (int s = 1; s < 4; ++s) {
    const float d = distc[(size_t)s * NP + n];
    if (d < bd) { bd = d; bi = idxc[(size_t)s * NP + n]; }  // tie keeps lower slab
  }
  idx_out[n] = bi;
}

// ---------------- residual in place: P^T[d][n] -= C1^T[d][idx1[n]] -----------
__global__ __launch_bounds__(256) void resid_kernel(float* __restrict__ PT,
                                                    const float* __restrict__ C1T,
                                                    const int* __restrict__ idx1) {
  const int d = blockIdx.y;
  const int n = blockIdx.x * 256 + threadIdx.x;
  const int k = idx1[n];
  PT[(size_t)d * NP + n] -= C1T[d * KC + k];
}

// ---------------- BN stats: per-channel sum & sumsq of LUT outputs -----------
__global__ __launch_bounds__(256) void stats_kernel(const int* __restrict__ idx1,
                                                    const int* __restrict__ idx2,
                                                    const float* __restrict__ dotc,
                                                    const float* __restrict__ dotrc,
                                                    float* __restrict__ gsum,
                                                    float* __restrict__ gsq) {
  __shared__ float ssum[4][128], ssq[4][128];
  const int tid = threadIdx.x, lane = tid & 63, wv = tid >> 6;
  const int wid = blockIdx.x * 4 + wv;           // 0..511
  float s0 = 0.f, s1 = 0.f, q0 = 0.f, q1 = 0.f;
  for (int n = wid; n < NP; n += 512) {          // 25088 = 512*49
    const int k1 = idx1[n], k2 = idx2[n];
    const float2 u = ((const float2*)(dotc + (size_t)k1 * 128))[lane];
    const float2 v = ((const float2*)(dotrc + (size_t)k2 * 128))[lane];
    const float x0 = u.x + v.x, x1 = u.y + v.y;
    s0 += x0; s1 += x1; q0 += x0 * x0; q1 += x1 * x1;
  }
  ssum[wv][lane * 2] = s0; ssum[wv][lane * 2 + 1] = s1;
  ssq[wv][lane * 2] = q0;  ssq[wv][lane * 2 + 1] = q1;
  __syncthreads();
  if (tid < 128) {
    const float s = ssum[0][tid] + ssum[1][tid] + ssum[2][tid] + ssum[3][tid];
    const float q = ssq[0][tid] + ssq[1][tid] + ssq[2][tid] + ssq[3][tid];
    atomicAdd(&gsum[tid], s);
    atomicAdd(&gsq[tid], q);
  }
}

__global__ void finalize_kernel(const float* __restrict__ gsum,
                                const float* __restrict__ gsq,
                                const float* __restrict__ gamma,
                                const float* __restrict__ beta,
                                float* __restrict__ scalev,
                                float* __restrict__ shiftv) {
  const int c = threadIdx.x;                     // 128
  const float mean = gsum[c] * (1.0f / NP);
  const float var = gsq[c] * (1.0f / NP) - mean * mean;
  const float inv = rsqrtf(var + 1e-5f);
  const float sc = gamma[c] * inv;
  scalev[c] = sc;
  shiftv[c] = beta[c] - mean * sc;
}

// ---------------- output: LUT gather + affine BN + [B,C,H,W] store -----------
__global__ __launch_bounds__(256) void output_kernel(const int* __restrict__ idx1,
                                                     const int* __restrict__ idx2,
                                                     const float* __restrict__ dotc,
                                                     const float* __restrict__ dotrc,
                                                     const float* __restrict__ scalev,
                                                     const float* __restrict__ shiftv,
                                                     float* __restrict__ out) {
  __shared__ float vals[64][128];                // [n-local][c]  32 KB
  const int tid = threadIdx.x, lane = tid & 63, wv = tid >> 6;
  const int blk = blockIdx.x;                    // 392 = 8 * 49
  const int b = blk / 49, hw0 = (blk % 49) * 64;
  const int n0 = b * 3136 + hw0;
  const float sc0 = scalev[lane * 2], sc1 = scalev[lane * 2 + 1];
  const float sh0 = shiftv[lane * 2], sh1 = shiftv[lane * 2 + 1];
  for (int t = 0; t < 16; ++t) {
    const int nn = wv * 16 + t;
    const int n = n0 + nn;
    const int k1 = idx1[n], k2 = idx2[n];
    const float2 u = ((const float2*)(dotc + (size_t)k1 * 128))[lane];
    const float2 v = ((const float2*)(dotrc + (size_t)k2 * 128))[lane];
    *(float2*)&vals[nn][lane * 2] =
        make_float2(sc0 * (u.x + v.x) + sh0, sc1 * (u.y + v.y) + sh1);
  }
  __syncthreads();
  const int c = tid >> 1, half = tid & 1;
  float* op = out + ((size_t)b * 128 + c) * 3136 + hw0 + half * 32;
#pragma unroll
  for (int i = 0; i < 32; i += 4) {
    float4 w4;
    w4.x = vals[half * 32 + i + 0][c];
    w4.y = vals[half * 32 + i + 1][c];
    w4.z = vals[half * 32 + i + 2][c];
    w4.w = vals[half * 32 + i + 3][c];
    *(float4*)(op + i) = w4;
  }
}

extern "C" void kernel_launch(void* const* d_in, const int* in_sizes, int n_in,
                              void* d_out, int out_size, void* d_ws, size_t ws_size,
                              hipStream_t stream) {
  const float* x     = (const float*)d_in[0];
  const float* cent  = (const float*)d_in[1];
  const float* rcent = (const float*)d_in[2];
  const float* dotc  = (const float*)d_in[3];
  const float* dotrc = (const float*)d_in[4];
  const float* gamma = (const float*)d_in[5];
  const float* beta  = (const float*)d_in[6];
  float* out = (float*)d_out;

  // workspace layout (~60 MB)
  float* PT  = (float*)d_ws;                 // [576][25088]
  float* C1T = PT + (size_t)DD * NP;         // [576][256]
  float* C2T = C1T + (size_t)DD * KC;        // [576][256]
  int* idx1  = (int*)(C2T + (size_t)DD * KC);
  int* idx2  = idx1 + NP;
  float* distc = (float*)(idx2 + NP);        // [4][25088]
  int* idxc    = (int*)(distc + 4 * NP);     // [4][25088]
  float* gsum   = (float*)(idxc + 4 * NP);   // [128]
  float* gsq    = gsum + 128;                // [128]
  float* scalev = gsq + 128;                 // [128]
  float* shiftv = scalev + 128;              // [128]

  unfold_kernel<<<dim3(98, 576), 256, 0, stream>>>(x, PT);
  transpose_kernel<<<576, 256, 0, stream>>>(cent, C1T);
  transpose_kernel<<<576, 256, 0, stream>>>(rcent, C2T);
  nearest_kernel<<<1568, 256, 0, stream>>>(PT, C1T, distc, idxc);
  combine_kernel<<<98, 256, 0, stream>>>(distc, idxc, idx1);
  resid_kernel<<<dim3(98, 576), 256, 0, stream>>>(PT, C1T, idx1);
  nearest_kernel<<<1568, 256, 0, stream>>>(PT, C2T, distc, idxc);
  combine_kernel<<<98, 256, 0, stream>>>(distc, idxc, idx2);
  hipMemsetAsync(gsum, 0, 256 * sizeof(float), stream);
  stats_kernel<<<128, 256, 0, stream>>>(idx1, idx2, dotc, dotrc, gsum, gsq);
  finalize_kernel<<<1, 128, 0, stream>>>(gsum, gsq, gamma, beta, scalev, shiftv);
  output_kernel<<<392, 256, 0, stream>>>(idx1, idx2, dotc, dotrc, scalev, shiftv, out);
}

// Round 12
// 665.888 us; speedup vs baseline: 18.2735x; 3.1792x over previous
//
#include <hip/hip_runtime.h>

#define NP 25088   // B * oH * oW = 8*56*56
#define DD 576     // 64 * 3 * 3
#define KC 256     // centroids

// ---------------- unfold: x[8,64,56,56] -> P^T[576][25088], d = c*9+i*3+j ----
__global__ __launch_bounds__(256) void unfold_kernel(const float* __restrict__ x,
                                                     float* __restrict__ PT) {
  const int d = blockIdx.y;                       // 0..575
  const int n = blockIdx.x * 256 + threadIdx.x;   // 0..25087
  const int c = d / 9, r = d % 9;
  const int di = r / 3 - 1, dj = r % 3 - 1;
  const int b = n / 3136, hw = n % 3136;
  const int h = hw / 56 + di, w = hw % 56 + dj;
  float v = 0.0f;
  if (h >= 0 && h < 56 && w >= 0 && w < 56)
    v = x[(((size_t)b * 64 + c) * 56 + h) * 56 + w];
  PT[(size_t)d * NP + n] = v;
}

// ---------------- centroid transpose: C[256][576] -> C^T[576][256] -----------
__global__ __launch_bounds__(256) void transpose_kernel(const float* __restrict__ C,
                                                        float* __restrict__ CT) {
  const int d = blockIdx.x;      // 576
  const int k = threadIdx.x;     // 256
  CT[d * KC + k] = C[k * DD + d];
}

// ---------------- nearest: per-block best over a 64-k slab -------------------
// R4 OPTIMUM RESTORED VERBATIM (287 us/dispatch, VGPR 44, zero scratch).
// 64m x 64k block, 4m x 4k thread tile, Dc=32 double-buffered, 32 KB LDS ->
// 5 blocks/CU = 20 waves/CU, grid 1568 = 392 m-groups x 4 k-slabs,
// XCD-chunk swizzled, launch_bounds(256,5), #pragma unroll 8 inner loop.
// The unroll-8 window is LOAD-BEARING: it bounds ds_read temporary live
// ranges (~20 regs). R11's full unroll let the scheduler hoist all 64
// ds_reads -> live-range explosion -> 3 GB scratch, 3.7x regression.
// FAILED departures (do not revisit): 4m x 8k @12w (R5), Dc=16 @24w (R6),
// global_load_lds DMA (R7), scalar-feed (R8), reg-dbuf rotation (R9),
// launch_bounds cap 64 (R10 spill catastrophe), full unroll (R11).
#define ACC4(p, a, s) \
  do { p.x += fabsf(a.x - (s)); p.y += fabsf(a.y - (s)); \
       p.z += fabsf(a.z - (s)); p.w += fabsf(a.w - (s)); } while (0)
#define ADD4(t, p) \
  do { t.x += p.x; t.y += p.y; t.z += p.z; t.w += p.w; } while (0)
#define COMP(v, i) ((i) == 0 ? (v).x : (i) == 1 ? (v).y : (i) == 2 ? (v).z : (v).w)

__global__ __launch_bounds__(256, 5) void nearest_kernel(const float* __restrict__ AT,
                                                         const float* __restrict__ CT,
                                                         float* __restrict__ distc,
                                                         int* __restrict__ idxc) {
  __shared__ float As[2][32][64];    // [buf][d][m]   16 KB
  __shared__ float Bs[2][32][64];    // [buf][d][k]   16 KB

  const int tid = threadIdx.x;
  const int tm = tid >> 4;           // 0..15 -> m = m0 + tm*4 + i
  const int tk = tid & 15;           // 0..15 -> k = k0 + tk*4 + j
  // XCD-chunk swizzle: XCD x gets m-groups [49x, 49x+49), 4 k-slabs adjacent.
  const int L = blockIdx.x;          // 0..1567 (= 8 * 196)
  const int xcd = L & 7, r = L >> 3;     // r 0..195
  const int mb = xcd * 49 + (r >> 2);    // 0..391
  const int kc = r & 3;                  // 0..3
  const int m0 = mb * 64, k0 = kc * 64;

  // staging + accumulators: named float4 only (no local arrays anywhere)
  float4 ra0, rb0;
  float4 p0, p1, p2, p3, t0, t1, t2, t3;

  const int frow = tid >> 4, fcol = (tid & 15) * 4;   // one row per 16 threads
  const float* ap = AT + (size_t)frow * NP + m0 + fcol;
  const float* bp = CT + (size_t)frow * KC + k0 + fcol;

#define LOADT() do {                                       \
    ra0 = *(const float4*)(ap);                            \
    rb0 = *(const float4*)(bp);                            \
    ap += (size_t)32 * NP; bp += 32 * KC;                  \
  } while (0)

#define LOADT2() do {                                      \
    ra1 = *(const float4*)(ap - (size_t)16 * NP);          \
    rb1 = *(const float4*)(bp - 16 * KC);                  \
  } while (0)

#define WRITET(bf) do {                                    \
    *(float4*)&As[bf][frow][fcol] = ra0;                   \
    *(float4*)&As[bf][16 + frow][fcol] = ra1;              \
    *(float4*)&Bs[bf][frow][fcol] = rb0;                   \
    *(float4*)&Bs[bf][16 + frow][fcol] = rb1;              \
  } while (0)

  float4 ra1, rb1;
  // prologue: load chunk 0 (rows frow and frow+16 of 32)
  ra0 = *(const float4*)(ap);
  ra1 = *(const float4*)(ap + (size_t)16 * NP);
  rb0 = *(const float4*)(bp);
  rb1 = *(const float4*)(bp + 16 * KC);
  ap += (size_t)32 * NP; bp += 32 * KC;
  WRITET(0);
  t0 = t1 = t2 = t3 = make_float4(0.f, 0.f, 0.f, 0.f);

  for (int ch = 0; ch < 18; ++ch) {            // 18 * 32 = 576 d's
    if ((ch & 1) == 0) p0 = p1 = p2 = p3 = make_float4(0.f, 0.f, 0.f, 0.f);
    __syncthreads();                           // staged buf (ch&1) visible
    if (ch < 17) {                             // issue next-chunk global loads
      ra0 = *(const float4*)(ap);
      ra1 = *(const float4*)(ap + (size_t)16 * NP);
      rb0 = *(const float4*)(bp);
      rb1 = *(const float4*)(bp + 16 * KC);
      ap += (size_t)32 * NP; bp += 32 * KC;
    }
    const float (*__restrict__ Asb)[64] = As[ch & 1];
    const float (*__restrict__ Bsb)[64] = Bs[ch & 1];
#pragma unroll 8
    for (int d = 0; d < 32; ++d) {
      const float4 a = *(const float4*)&Asb[d][tm * 4];
      const float4 b = *(const float4*)&Bsb[d][tk * 4];
      ACC4(p0, a, b.x);
      ACC4(p1, a, b.y);
      ACC4(p2, a, b.z);
      ACC4(p3, a, b.w);
    }
    if (ch < 17) WRITET((ch + 1) & 1);         // ds_write after compute (T14)
    if (ch & 1) {                              // segment flush (64 d's)
      ADD4(t0, p0); ADD4(t1, p1); ADD4(t2, p2); ADD4(t3, p3);
    }
  }

  // per-thread argmin over its 4 k's (ascending, strict < => first-min),
  // then butterfly reduce across the 16 tk lanes sharing this m-row.
#pragma unroll
  for (int i = 0; i < 4; ++i) {
    const float d0 = COMP(t0, i), d1 = COMP(t1, i), d2 = COMP(t2, i), d3 = COMP(t3, i);
    float bd = d0;
    int bk = k0 + tk * 4;
    if (d1 < bd) { bd = d1; bk = k0 + tk * 4 + 1; }
    if (d2 < bd) { bd = d2; bk = k0 + tk * 4 + 2; }
    if (d3 < bd) { bd = d3; bk = k0 + tk * 4 + 3; }
#pragma unroll
    for (int off = 1; off < 16; off <<= 1) {
      const float od = __shfl_xor(bd, off, 64);
      const int ok = __shfl_xor(bk, off, 64);
      if (od < bd || (od == bd && ok < bk)) { bd = od; bk = ok; }
    }
    if (tk == 0) {
      const int m = m0 + tm * 4 + i;
      distc[(size_t)kc * NP + m] = bd;
      idxc[(size_t)kc * NP + m] = bk;
    }
  }
#undef LOADT
#undef LOADT2
#undef WRITET
}

// ---------------- combine the four k-slab candidates (tie -> lower k) --------
__global__ __launch_bounds__(256) void combine_kernel(const float* __restrict__ distc,
                                                      const int* __restrict__ idxc,
                                                      int* __restrict__ idx_out) {
  const int n = blockIdx.x * 256 + threadIdx.x;
  if (n >= NP) return;
  float bd = distc[n];
  int bi = idxc[n];
#pragma unroll
  for (int s = 1; s < 4; ++s) {
    const float d = distc[(size_t)s * NP + n];
    if (d < bd) { bd = d; bi = idxc[(size_t)s * NP + n]; }  // tie keeps lower slab
  }
  idx_out[n] = bi;
}

// ---------------- residual in place: P^T[d][n] -= C1^T[d][idx1[n]] -----------
__global__ __launch_bounds__(256) void resid_kernel(float* __restrict__ PT,
                                                    const float* __restrict__ C1T,
                                                    const int* __restrict__ idx1) {
  const int d = blockIdx.y;
  const int n = blockIdx.x * 256 + threadIdx.x;
  const int k = idx1[n];
  PT[(size_t)d * NP + n] -= C1T[d * KC + k];
}

// ---------------- BN stats: per-channel sum & sumsq of LUT outputs -----------
__global__ __launch_bounds__(256) void stats_kernel(const int* __restrict__ idx1,
                                                    const int* __restrict__ idx2,
                                                    const float* __restrict__ dotc,
                                                    const float* __restrict__ dotrc,
                                                    float* __restrict__ gsum,
                                                    float* __restrict__ gsq) {
  __shared__ float ssum[4][128], ssq[4][128];
  const int tid = threadIdx.x, lane = tid & 63, wv = tid >> 6;
  const int wid = blockIdx.x * 4 + wv;           // 0..511
  float s0 = 0.f, s1 = 0.f, q0 = 0.f, q1 = 0.f;
  for (int n = wid; n < NP; n += 512) {          // 25088 = 512*49
    const int k1 = idx1[n], k2 = idx2[n];
    const float2 u = ((const float2*)(dotc + (size_t)k1 * 128))[lane];
    const float2 v = ((const float2*)(dotrc + (size_t)k2 * 128))[lane];
    const float x0 = u.x + v.x, x1 = u.y + v.y;
    s0 += x0; s1 += x1; q0 += x0 * x0; q1 += x1 * x1;
  }
  ssum[wv][lane * 2] = s0; ssum[wv][lane * 2 + 1] = s1;
  ssq[wv][lane * 2] = q0;  ssq[wv][lane * 2 + 1] = q1;
  __syncthreads();
  if (tid < 128) {
    const float s = ssum[0][tid] + ssum[1][tid] + ssum[2][tid] + ssum[3][tid];
    const float q = ssq[0][tid] + ssq[1][tid] + ssq[2][tid] + ssq[3][tid];
    atomicAdd(&gsum[tid], s);
    atomicAdd(&gsq[tid], q);
  }
}

__global__ void finalize_kernel(const float* __restrict__ gsum,
                                const float* __restrict__ gsq,
                                const float* __restrict__ gamma,
                                const float* __restrict__ beta,
                                float* __restrict__ scalev,
                                float* __restrict__ shiftv) {
  const int c = threadIdx.x;                     // 128
  const float mean = gsum[c] * (1.0f / NP);
  const float var = gsq[c] * (1.0f / NP) - mean * mean;
  const float inv = rsqrtf(var + 1e-5f);
  const float sc = gamma[c] * inv;
  scalev[c] = sc;
  shiftv[c] = beta[c] - mean * sc;
}

// ---------------- output: LUT gather + affine BN + [B,C,H,W] store -----------
__global__ __launch_bounds__(256) void output_kernel(const int* __restrict__ idx1,
                                                     const int* __restrict__ idx2,
                                                     const float* __restrict__ dotc,
                                                     const float* __restrict__ dotrc,
                                                     const float* __restrict__ scalev,
                                                     const float* __restrict__ shiftv,
                                                     float* __restrict__ out) {
  __shared__ float vals[64][128];                // [n-local][c]  32 KB
  const int tid = threadIdx.x, lane = tid & 63, wv = tid >> 6;
  const int blk = blockIdx.x;                    // 392 = 8 * 49
  const int b = blk / 49, hw0 = (blk % 49) * 64;
  const int n0 = b * 3136 + hw0;
  const float sc0 = scalev[lane * 2], sc1 = scalev[lane * 2 + 1];
  const float sh0 = shiftv[lane * 2], sh1 = shiftv[lane * 2 + 1];
  for (int t = 0; t < 16; ++t) {
    const int nn = wv * 16 + t;
    const int n = n0 + nn;
    const int k1 = idx1[n], k2 = idx2[n];
    const float2 u = ((const float2*)(dotc + (size_t)k1 * 128))[lane];
    const float2 v = ((const float2*)(dotrc + (size_t)k2 * 128))[lane];
    *(float2*)&vals[nn][lane * 2] =
        make_float2(sc0 * (u.x + v.x) + sh0, sc1 * (u.y + v.y) + sh1);
  }
  __syncthreads();
  const int c = tid >> 1, half = tid & 1;
  float* op = out + ((size_t)b * 128 + c) * 3136 + hw0 + half * 32;
#pragma unroll
  for (int i = 0; i < 32; i += 4) {
    float4 w4;
    w4.x = vals[half * 32 + i + 0][c];
    w4.y = vals[half * 32 + i + 1][c];
    w4.z = vals[half * 32 + i + 2][c];
    w4.w = vals[half * 32 + i + 3][c];
    *(float4*)(op + i) = w4;
  }
}

extern "C" void kernel_launch(void* const* d_in, const int* in_sizes, int n_in,
                              void* d_out, int out_size, void* d_ws, size_t ws_size,
                              hipStream_t stream) {
  const float* x     = (const float*)d_in[0];
  const float* cent  = (const float*)d_in[1];
  const float* rcent = (const float*)d_in[2];
  const float* dotc  = (const float*)d_in[3];
  const float* dotrc = (const float*)d_in[4];
  const float* gamma = (const float*)d_in[5];
  const float* beta  = (const float*)d_in[6];
  float* out = (float*)d_out;

  // workspace layout (~60 MB)
  float* PT  = (float*)d_ws;                 // [576][25088]
  float* C1T = PT + (size_t)DD * NP;         // [576][256]
  float* C2T = C1T + (size_t)DD * KC;        // [576][256]
  int* idx1  = (int*)(C2T + (size_t)DD * KC);
  int* idx2  = idx1 + NP;
  float* distc = (float*)(idx2 + NP);        // [4][25088]
  int* idxc    = (int*)(distc + 4 * NP);     // [4][25088]
  float* gsum   = (float*)(idxc + 4 * NP);   // [128]
  float* gsq    = gsum + 128;                // [128]
  float* scalev = gsq + 128;                 // [128]
  float* shiftv = scalev + 128;              // [128]

  unfold_kernel<<<dim3(98, 576), 256, 0, stream>>>(x, PT);
  transpose_kernel<<<576, 256, 0, stream>>>(cent, C1T);
  transpose_kernel<<<576, 256, 0, stream>>>(rcent, C2T);
  nearest_kernel<<<1568, 256, 0, stream>>>(PT, C1T, distc, idxc);
  combine_kernel<<<98, 256, 0, stream>>>(distc, idxc, idx1);
  resid_kernel<<<dim3(98, 576), 256, 0, stream>>>(PT, C1T, idx1);
  nearest_kernel<<<1568, 256, 0, stream>>>(PT, C2T, distc, idxc);
  combine_kernel<<<98, 256, 0, stream>>>(distc, idxc, idx2);
  hipMemsetAsync(gsum, 0, 256 * sizeof(float), stream);
  stats_kernel<<<128, 256, 0, stream>>>(idx1, idx2, dotc, dotrc, gsum, gsq);
  finalize_kernel<<<1, 128, 0, stream>>>(gsum, gsq, gamma, beta, scalev, shiftv);
  output_kernel<<<392, 256, 0, stream>>>(idx1, idx2, dotc, dotrc, scalev, shiftv, out);
}